// Round 5
// baseline (165.675 us; speedup 1.0000x reference)
//
#include <hip/hip_runtime.h>

typedef short short8 __attribute__((ext_vector_type(8)));
typedef short short4v __attribute__((ext_vector_type(4)));
typedef float floatx4 __attribute__((ext_vector_type(4)));

#define BB 4
#define CC 124
#define CP 128
#define NN 4096
#define NGRP 256               // 16-key groups per batch
#define NSPLIT 8
#define KSPLIT (NN / NSPLIT)   // 512 keys per split
#define TN 32                  // keys per chunk
#define NCHUNK (KSPLIT / TN)   // 16

static __device__ __forceinline__ unsigned short f2bf_fast(float f) {
    return (unsigned short)((__float_as_uint(f) + 0x8000u) >> 16);
}
static __device__ __forceinline__ float bf2f(unsigned short u) {
    return __uint_as_float(((unsigned int)u) << 16);
}
// pack bf16(a) (low16) | bf16(b) (high16): 2 adds + 1 v_perm (vs 10 ops naive)
static __device__ __forceinline__ unsigned int pkbf(float a, float b) {
    unsigned int ua = __float_as_uint(a) + 0x8000u;
    unsigned int ub = __float_as_uint(b) + 0x8000u;
    return __builtin_amdgcn_perm(ub, ua, 0x07060302u);
}
union PK2 { short4v s; unsigned int u[2]; };

// async global->LDS: 16B/lane, lds dest = wave-uniform base + lane*16
static __device__ __forceinline__ void gl16(const unsigned short* g, unsigned short* l) {
    __builtin_amdgcn_global_load_lds(
        (const __attribute__((address_space(1))) unsigned int*)g,
        (__attribute__((address_space(3))) unsigned int*)l, 16, 0, 0);
}

// ---------------------------------------------------------------------------
// Projection Bf = Wb x -> bf16 in MFMA-fragment order:
//  kfrag[b][g][t][lane]*8 : 16B = Bf[n=g*16+(lane&15)][c=t*32+(lane>>4)*8 ..+8]
//  vfrag[b][g][s8][lane]*4:  8B = Bf[c=s8*16+(lane&15)][n=g*16+(lane>>4)*4 ..+4]
// V channel 124 (zero pad) is set to 1.0 -> PV MFMA computes l = sum_n P[m][n]
// for free in O[m][124]. kfrag pads stay 0 (they sit in the QK K-dim).
// m2[b][n] = log2(e)*||Bf[:,n]||^2: fixed softmax stabilizer (diagonal is the
// row max with ~80 margin in exp2 space).
// W staged transposed bf16 in LDS: one ds_read_b64 per c-iter (was 8x b32).
// ---------------------------------------------------------------------------
__global__ __launch_bounds__(256) void bf_proj_kernel(const float* __restrict__ x,
                                                      const float* __restrict__ Wb,
                                                      unsigned short* __restrict__ kfrag,
                                                      unsigned short* __restrict__ vfrag,
                                                      float* __restrict__ m2) {
    __shared__ __align__(16) float xs[CC][36];            // 32-wide n tile
    __shared__ __align__(16) unsigned short wt[CC][CP];   // W^T bf16, rows o 124..127 = 0
    __shared__ float msh[32][32];
    const int tid = threadIdx.x;
    const int b = blockIdx.y;
    const int n0 = blockIdx.x * 32;
    const float* xb = x + (size_t)b * CC * NN + n0;
    for (int i = tid; i < CC * 8; i += 256) {
        int c = i >> 3, nq = i & 7;
        *(floatx4*)&xs[c][nq * 4] = *(const floatx4*)(xb + (size_t)c * NN + nq * 4);
    }
    for (int i = tid; i < CC * CP; i += 256) {
        int c = i >> 7, o = i & 127;
        wt[c][o] = (o < CC) ? f2bf_fast(Wb[o * CC + c]) : (unsigned short)0;
    }
    __syncthreads();
    const int og = tid >> 3;        // 0..31 -> o0 = og*4
    const int nidx = tid & 7;       // -> n = n0 + nidx*4 + j
    const int o0 = og * 4;
    float acc[4][4];
#pragma unroll
    for (int k = 0; k < 4; ++k)
#pragma unroll
        for (int j = 0; j < 4; ++j) acc[k][j] = 0.f;
    for (int c = 0; c < CC; ++c) {
        floatx4 xv = *(const floatx4*)&xs[c][nidx * 4];
        short4v wv = *(const short4v*)&wt[c][o0];
#pragma unroll
        for (int k = 0; k < 4; ++k) {
            float wf = bf2f((unsigned short)wv[k]);
            acc[k][0] += wf * xv[0];
            acc[k][1] += wf * xv[1];
            acc[k][2] += wf * xv[2];
            acc[k][3] += wf * xv[3];
        }
    }
    // stats
    float sq[4] = {0.f, 0.f, 0.f, 0.f};
#pragma unroll
    for (int k = 0; k < 4; ++k)
#pragma unroll
        for (int j = 0; j < 4; ++j) sq[j] += acc[k][j] * acc[k][j];
    // kfrag: per j, 4 consecutive c-values (half a 16B unit)
    const int g = (n0 >> 4) + (nidx >> 2);
    const int tK = o0 >> 5;
    const int qK = (o0 >> 3) & 3;
    const int half = o0 & 7;        // 0 or 4 shorts
#pragma unroll
    for (int j = 0; j < 4; ++j) {
        PK2 kv;
        kv.u[0] = pkbf(acc[0][j], acc[1][j]);
        kv.u[1] = pkbf(acc[2][j], acc[3][j]);
        size_t unit = ((size_t)(b * NGRP + g) * 4 + tK) * 64 + qK * 16 + ((nidx & 3) * 4 + j);
        *(short4v*)&kfrag[unit * 8 + half] = kv.s;
    }
    // vfrag: per k, 4 consecutive n-values (one 8B unit); c==124 -> ones
#pragma unroll
    for (int k = 0; k < 4; ++k) {
        int c = o0 + k;
        PK2 vv;
        if (c == 124) {
            vv.u[0] = 0x3f803f80u;
            vv.u[1] = 0x3f803f80u;
        } else {
            vv.u[0] = pkbf(acc[k][0], acc[k][1]);
            vv.u[1] = pkbf(acc[k][2], acc[k][3]);
        }
        size_t unit = ((size_t)(b * NGRP + g) * 8 + (c >> 4)) * 64 + (nidx & 3) * 16 + (c & 15);
        *(short4v*)&vfrag[unit * 4] = vv.s;
    }
#pragma unroll
    for (int j = 0; j < 4; ++j) msh[og][nidx * 4 + j] = sq[j];
    __syncthreads();
    if (tid < 32) {
        float s = 0.f;
#pragma unroll
        for (int og2 = 0; og2 < 32; ++og2) s += msh[og2][tid];
        m2[(size_t)b * NN + n0 + tid] = s * 1.44269504088896340736f;
    }
}

// ---------------------------------------------------------------------------
// Flash attention: async global_load_lds staging (pre-fragmented K/V),
// double-buffered 32-key chunks (32KB LDS -> 4 blocks/CU, 16 waves/CU),
// operand-swapped QK keeps P in registers; l comes free from V's ones-column.
// ---------------------------------------------------------------------------
__global__ __launch_bounds__(256, 4) void attn_kernel(const unsigned short* __restrict__ kfrag,
                                                      const unsigned short* __restrict__ vfrag,
                                                      const float* __restrict__ m2,
                                                      unsigned short* __restrict__ opart) {
    __shared__ __align__(16) unsigned short kbuf[2][8 * 512];   // 8KB / buffer
    __shared__ __align__(16) unsigned short vbuf[2][8 * 512];   // 8KB / buffer
    // XCD x (= id%8) serves grps {4x..4x+3}: ~1MB L2-resident stream per XCD
    const int id = blockIdx.x;
    const int ghi = id & 7;
    const int r_ = id >> 3;
    const int mtile = r_ & 31;
    const int glo = r_ >> 5;          // 0..3
    const int grp = ghi * 4 + glo;    // 0..31
    const int b = grp & 3;
    const int split = grp >> 2;       // 0..7
    const int w = threadIdx.x >> 6;
    const int lane = threadIdx.x & 63;
    const int col = lane & 15;
    const int m0 = mtile * 128 + w * 32;
    const int gsplit = split * (KSPLIT / 16);   // first group of this split
    const floatx4 fzero = {0.f, 0.f, 0.f, 0.f};
    const float L2E = 1.44269504088896340736f;

    // Q frags (B operand of swapped QK), resident in registers
    short8 qf[2][4];
#pragma unroll
    for (int ms = 0; ms < 2; ++ms) {
        const int gq = (m0 >> 4) + ms;
#pragma unroll
        for (int t = 0; t < 4; ++t)
            qf[ms][t] = *(const short8*)&kfrag[(((size_t)(b * NGRP + gq) * 4 + t) * 64 + lane) * 8];
    }
    float mreg[2];
    mreg[0] = m2[(size_t)b * NN + m0 + col];
    mreg[1] = m2[(size_t)b * NN + m0 + 16 + col];

    floatx4 oacc[2][8];
#pragma unroll
    for (int ms = 0; ms < 2; ++ms)
#pragma unroll
        for (int s8 = 0; s8 < 8; ++s8) oacc[ms][s8] = fzero;

    // 16 x 1KB pieces per chunk (8 K + 8 V); wave w stages pieces w*4..w*4+3
    auto stage = [&](int ch, int sel) {
        const int gbase = gsplit + ch * 2;
        if (w < 2) {
#pragma unroll
            for (int i = 0; i < 4; ++i) {
                int p = w * 4 + i;
                const unsigned short* src =
                    kfrag + (size_t)(b * NGRP + gbase + (p >> 2)) * 2048 + (p & 3) * 512 + lane * 8;
                gl16(src, &kbuf[sel][p * 512]);
            }
        } else {
#pragma unroll
            for (int i = 0; i < 4; ++i) {
                int q = (w - 2) * 4 + i;
                const unsigned short* src =
                    vfrag + (size_t)(b * NGRP + gbase + (q >> 2)) * 2048 + (q & 3) * 512 + lane * 8;
                gl16(src, &vbuf[sel][q * 512]);
            }
        }
    };

    stage(0, 0);
#pragma unroll 2
    for (int ch = 0; ch < NCHUNK; ++ch) {
        const int sel = ch & 1;
        __syncthreads();                       // drains staging DMA + guards buffer reuse
        if (ch + 1 < NCHUNK) stage(ch + 1, sel ^ 1);
        // ---- S^T = K Q^T over 32 keys (operand-swapped) ----
        floatx4 st[2][2];
#pragma unroll
        for (int ms = 0; ms < 2; ++ms)
#pragma unroll
            for (int u = 0; u < 2; ++u) st[ms][u] = fzero;
#pragma unroll
        for (int t = 0; t < 4; ++t) {
#pragma unroll
            for (int u = 0; u < 2; ++u) {
                short8 kf = *(const short8*)&kbuf[sel][((u * 4 + t) * 64 + lane) * 8];
                st[0][u] = __builtin_amdgcn_mfma_f32_16x16x32_bf16(kf, qf[0][t], st[0][u], 0, 0, 0);
                st[1][u] = __builtin_amdgcn_mfma_f32_16x16x32_bf16(kf, qf[1][t], st[1][u], 0, 0, 0);
            }
        }
        // ---- softmax numerator -> PV A-frags (registers only, v_perm pack) ----
        short4v af[2][2];
#pragma unroll
        for (int ms = 0; ms < 2; ++ms) {
#pragma unroll
            for (int u = 0; u < 2; ++u) {
                float p0 = exp2f(__builtin_fmaf(st[ms][u][0], L2E, -mreg[ms]));
                float p1 = exp2f(__builtin_fmaf(st[ms][u][1], L2E, -mreg[ms]));
                float p2 = exp2f(__builtin_fmaf(st[ms][u][2], L2E, -mreg[ms]));
                float p3 = exp2f(__builtin_fmaf(st[ms][u][3], L2E, -mreg[ms]));
                PK2 pk;
                pk.u[0] = pkbf(p0, p1);
                pk.u[1] = pkbf(p2, p3);
                af[ms][u] = pk.s;
            }
        }
        // ---- O += P V (K=16 MFMAs; P already in A-layout) ----
#pragma unroll
        for (int u = 0; u < 2; ++u) {
#pragma unroll
            for (int s8 = 0; s8 < 8; ++s8) {
                short4v vf = *(const short4v*)&vbuf[sel][((u * 8 + s8) * 64 + lane) * 4];
                oacc[0][s8] = __builtin_amdgcn_mfma_f32_16x16x16bf16_1k(af[0][u], vf, oacc[0][s8], 0, 0, 0);
                oacc[1][s8] = __builtin_amdgcn_mfma_f32_16x16x16bf16_1k(af[1][u], vf, oacc[1][s8], 0, 0, 0);
            }
        }
    }
    // ---- epilogue: bf16 unnormalized partials (channel 124 = partial l) ----
    const int quad = lane >> 4;
    unsigned short* ob = opart + (size_t)(split * BB + b) * NN * CP;
#pragma unroll
    for (int ms = 0; ms < 2; ++ms)
#pragma unroll
        for (int s8 = 0; s8 < 8; ++s8)
#pragma unroll
            for (int r = 0; r < 4; ++r)
                ob[(size_t)(m0 + ms * 16 + quad * 4 + r) * CP + s8 * 16 + col] = f2bf_fast(oacc[ms][s8][r]);
}

// ---------------------------------------------------------------------------
// Linear combine of 8 split partials (L read from channel 124) + normalize +
// gamma*E + x; LDS transpose for contiguous [b][c][m] writes.
// ---------------------------------------------------------------------------
__global__ __launch_bounds__(256) void combine_kernel(const unsigned short* __restrict__ opart,
                                                      const float* __restrict__ x,
                                                      const float* __restrict__ gamma,
                                                      float* __restrict__ out) {
    __shared__ float es[32 * 133];
    __shared__ float Lsh[32];
    const int t = threadIdx.x;
    const int b = blockIdx.y;
    const int m0 = blockIdx.x * 32;
    if (t < 32) {
        float L = 0.f;
#pragma unroll
        for (int s = 0; s < NSPLIT; ++s)
            L += bf2f(opart[((size_t)(s * BB + b) * NN + m0 + t) * CP + 124]);
        Lsh[t] = gamma[0] / L;
    }
    const int tc = t & 31, tm = t >> 5;
    float acc[4][4];
#pragma unroll
    for (int i = 0; i < 4; ++i)
#pragma unroll
        for (int j = 0; j < 4; ++j) acc[i][j] = 0.f;
    for (int s = 0; s < NSPLIT; ++s) {
        const unsigned short* obp = opart + ((size_t)(s * BB + b) * NN + m0 + tm * 4) * CP + tc * 4;
#pragma unroll
        for (int i = 0; i < 4; ++i) {
            short4v v = *(const short4v*)(obp + (size_t)i * CP);
            acc[i][0] += bf2f((unsigned short)v[0]);
            acc[i][1] += bf2f((unsigned short)v[1]);
            acc[i][2] += bf2f((unsigned short)v[2]);
            acc[i][3] += bf2f((unsigned short)v[3]);
        }
    }
#pragma unroll
    for (int i = 0; i < 4; ++i)
#pragma unroll
        for (int j = 0; j < 4; ++j) es[(tm * 4 + i) * 133 + tc * 4 + j] = acc[i][j];
    __syncthreads();
    const int wave = t >> 6, lane = t & 63;
    const int half = lane >> 5, lm = lane & 31;
#pragma unroll
    for (int p = 0; p < 16; ++p) {
        int c = p * 8 + wave * 2 + half;
        if (c < CC) {
            size_t base = ((size_t)b * CC + c) * NN + m0 + lm;
            out[base] = es[lm * 133 + c] * Lsh[lm] + x[base];
        }
    }
}

extern "C" void kernel_launch(void* const* d_in, const int* in_sizes, int n_in,
                              void* d_out, int out_size, void* d_ws, size_t ws_size,
                              hipStream_t stream) {
    const float* x = (const float*)d_in[0];
    const float* Wb = (const float*)d_in[1];
    const float* gamma = (const float*)d_in[2];
    float* out = (float*)d_out;

    const size_t kfrag_b = (size_t)BB * NGRP * 4 * 64 * 8 * sizeof(unsigned short);   // 4 MB
    const size_t vfrag_b = (size_t)BB * NGRP * 8 * 64 * 4 * sizeof(unsigned short);   // 4 MB
    const size_t m2_b = (size_t)BB * NN * sizeof(float);                               // 64 KB
    const size_t opart_b = (size_t)NSPLIT * BB * NN * CP * sizeof(unsigned short);     // 32 MB
    if (ws_size < kfrag_b + vfrag_b + m2_b + opart_b) return;

    char* w = (char*)d_ws;
    unsigned short* kfrag = (unsigned short*)w;
    unsigned short* vfrag = (unsigned short*)(w + kfrag_b);
    float* m2 = (float*)(w + kfrag_b + vfrag_b);
    unsigned short* opart = (unsigned short*)(w + kfrag_b + vfrag_b + m2_b);

    bf_proj_kernel<<<dim3(NN / 32, BB), 256, 0, stream>>>(x, Wb, kfrag, vfrag, m2);
    attn_kernel<<<dim3(1024), 256, 0, stream>>>(kfrag, vfrag, m2, opart);
    combine_kernel<<<dim3(NN / 32, BB), 256, 0, stream>>>(opart, x, gamma, out);
}

// Round 6
// 131.691 us; speedup vs baseline: 1.2581x; 1.2581x over previous
//
#include <hip/hip_runtime.h>

typedef short short8 __attribute__((ext_vector_type(8)));
typedef short short4v __attribute__((ext_vector_type(4)));
typedef float floatx4 __attribute__((ext_vector_type(4)));

#define BB 4
#define CC 124
#define CP 128
#define NN 4096
#define NGRP 256               // 16-position groups per batch (kfrag)
#define NG32 128               // 32-key groups per batch (vfrag)
#define NSPLIT 4
#define KSPLIT (NN / NSPLIT)   // 1024 keys per split
#define TN 64                  // keys per chunk
#define NCHUNK (KSPLIT / TN)   // 16

static __device__ __forceinline__ unsigned short f2bf_fast(float f) {
    return (unsigned short)((__float_as_uint(f) + 0x8000u) >> 16);
}
static __device__ __forceinline__ float bf2f(unsigned short u) {
    return __uint_as_float(((unsigned int)u) << 16);
}
// pack bf16(a) low16 | bf16(b) high16: 2 adds + 1 v_perm
static __device__ __forceinline__ unsigned int pkbf(float a, float b) {
    unsigned int ua = __float_as_uint(a) + 0x8000u;
    unsigned int ub = __float_as_uint(b) + 0x8000u;
    return __builtin_amdgcn_perm(ub, ua, 0x07060302u);
}
union PK2 { short4v s; unsigned int u[2]; };
union PK8 { short8 s; unsigned int u[4]; };

// async global->LDS: 16B/lane, lds dest = wave-uniform base + lane*16
static __device__ __forceinline__ void gl16(const unsigned short* g, unsigned short* l) {
    __builtin_amdgcn_global_load_lds(
        (const __attribute__((address_space(1))) unsigned int*)g,
        (__attribute__((address_space(3))) unsigned int*)l, 16, 0, 0);
}

// ---------------------------------------------------------------------------
// One-time Wb transpose -> wbt[c][o] bf16 (o padded to 128 with zeros).
// Coalesced Wb reads, LDS transpose (stride-125 conflict-free), coalesced writes.
// ---------------------------------------------------------------------------
__global__ __launch_bounds__(256) void wtrans_kernel(const float* __restrict__ Wb,
                                                     unsigned short* __restrict__ wbt) {
    __shared__ float ws[32][125];
    const int blk = blockIdx.x;      // o-range blk*32 .. +31
    const int tid = threadIdx.x;
    for (int i = tid; i < 32 * CC; i += 256) {
        int ol = i / CC, c = i - ol * CC;
        int o = blk * 32 + ol;
        ws[ol][c] = (o < CC) ? Wb[o * CC + c] : 0.f;
    }
    __syncthreads();
    for (int i = tid; i < CC * 32; i += 256) {
        int c = i >> 5, ol = i & 31;
        wbt[c * CP + blk * 32 + ol] = f2bf_fast(ws[ol][c]);
    }
}

// ---------------------------------------------------------------------------
// Projection Bf = Wb x -> bf16 MFMA fragments, with the PV-enabling KEY
// PERMUTATION baked in:  position p within each 32-block = 16*((n>>2)&1) +
// 4*((n>>3)&3) + (n&3).  kfrag is position-indexed (QK A and Q B operands);
// vfrag is K=32 B-frag layout in ACTUAL key order:
//   vfrag[b][g32][s8][lane]*8 : 16B = V[keys 8*quad..+8][c = s8*16+col]
// V channel 124 = 1.0 -> PV computes l in O[m][124] for free.
// m2[b][n] = log2(e)*||Bf[:,n]||^2 (fixed stabilizer; diagonal dominates).
// Wb read from global wbt (L1-resident 32KB broadcast) -- no W in LDS.
// ---------------------------------------------------------------------------
__global__ __launch_bounds__(256, 4) void bf_proj_kernel(const float* __restrict__ x,
                                                         const unsigned short* __restrict__ wbt,
                                                         unsigned short* __restrict__ kfrag,
                                                         unsigned short* __restrict__ vfrag,
                                                         float* __restrict__ m2) {
    __shared__ __align__(16) float xs[CC][36];
    __shared__ float msh[32][33];
    const int tid = threadIdx.x;
    const int b = blockIdx.y;
    const int n0 = blockIdx.x * 32;
    const float* xb = x + (size_t)b * CC * NN + n0;
    for (int i = tid; i < CC * 8; i += 256) {
        int c = i >> 3, nq = i & 7;
        *(floatx4*)&xs[c][nq * 4] = *(const floatx4*)(xb + (size_t)c * NN + nq * 4);
    }
    __syncthreads();
    const int og = tid >> 3;        // 0..31 -> o0 = og*4
    const int nidx = tid & 7;       // key n_loc = nidx*4 + j
    const int o0 = og * 4;
    float acc[4][4];
#pragma unroll
    for (int k = 0; k < 4; ++k)
#pragma unroll
        for (int j = 0; j < 4; ++j) acc[k][j] = 0.f;
    for (int c = 0; c < CC; ++c) {
        floatx4 xv = *(const floatx4*)&xs[c][nidx * 4];
        short4v wv = *(const short4v*)&wbt[c * CP + o0];
#pragma unroll
        for (int k = 0; k < 4; ++k) {
            float wf = bf2f((unsigned short)wv[k]);
            acc[k][0] += wf * xv[0];
            acc[k][1] += wf * xv[1];
            acc[k][2] += wf * xv[2];
            acc[k][3] += wf * xv[3];
        }
    }
    // stats (per-n partial over this thread's 4 channels)
    float sq[4] = {0.f, 0.f, 0.f, 0.f};
#pragma unroll
    for (int k = 0; k < 4; ++k)
#pragma unroll
        for (int j = 0; j < 4; ++j) sq[j] += acc[k][j] * acc[k][j];
#pragma unroll
    for (int j = 0; j < 4; ++j) msh[og][nidx * 4 + j] = sq[j];
    // ---- kfrag (position-permuted) ----
    const int g16 = (n0 >> 4) + (nidx & 1);      // (n0>>5)*2 + (nidx&1)
    const int tK = o0 >> 5;
    const int qK = (o0 >> 3) & 3;
    const int halfo = o0 & 7;                    // 0 or 4 shorts
#pragma unroll
    for (int j = 0; j < 4; ++j) {
        PK2 kv;
        kv.u[0] = pkbf(acc[0][j], acc[1][j]);
        kv.u[1] = pkbf(acc[2][j], acc[3][j]);
        int row16 = 4 * (nidx >> 1) + j;         // p & 15
        size_t unit = ((size_t)(b * NGRP + g16) * 4 + tK) * 64 + qK * 16 + row16;
        *(short4v*)&kfrag[unit * 8 + halfo] = kv.s;
    }
    // ---- vfrag (K=32 B-frags, natural key order) ----
    const int g32 = n0 >> 5;
    const int quadn = nidx >> 1;                 // (n_loc)>>3
    const int halfn = (nidx & 1) * 4;            // element offset j_in_8 base
#pragma unroll
    for (int k = 0; k < 4; ++k) {
        int c = o0 + k;
        PK2 vv;
        if (c == 124) {
            vv.u[0] = 0x3f803f80u;
            vv.u[1] = 0x3f803f80u;
        } else {
            vv.u[0] = pkbf(acc[k][0], acc[k][1]);
            vv.u[1] = pkbf(acc[k][2], acc[k][3]);
        }
        size_t unit = ((size_t)(b * NG32 + g32) * 8 + (c >> 4)) * 64 + quadn * 16 + (c & 15);
        *(short4v*)&vfrag[unit * 8 + halfn] = vv.s;
    }
    __syncthreads();
    if (tid < 32) {
        float s = 0.f;
#pragma unroll
        for (int og2 = 0; og2 < 32; ++og2) s += msh[og2][tid];
        m2[(size_t)b * NN + n0 + tid] = s * 1.44269504088896340736f;
    }
}

// ---------------------------------------------------------------------------
// Flash attention: async-staged pre-fragmented K/V, double-buffered 64-key
// chunks, operand-swapped QK; thanks to the key permutation, S^T's C-layout
// IS the K=32 PV A-fragment -> PV uses full-rate mfma_f32_16x16x32_bf16.
// Zero cross-lane ops in the hot loop; l free via V's ones-column.
// ---------------------------------------------------------------------------
__global__ __launch_bounds__(256, 2) void attn_kernel(const unsigned short* __restrict__ kfrag,
                                                      const unsigned short* __restrict__ vfrag,
                                                      const float* __restrict__ m2,
                                                      unsigned short* __restrict__ opart) {
    __shared__ __align__(16) unsigned short kbuf[2][16 * 512];   // 16 KB each
    __shared__ __align__(16) unsigned short vbuf[2][16 * 512];   // 16 KB each
    // XCD x (= id%8) serves grps {2x,2x+1}: ~1MB L2-resident stream per XCD
    const int id = blockIdx.x;
    const int ghi = id & 7;
    const int r_ = id >> 3;
    const int mtile = r_ & 31;
    const int glo = r_ >> 5;          // 0..1
    const int grp = ghi * 2 + glo;    // 0..15
    const int b = grp & 3;
    const int split = grp >> 2;       // 0..3
    const int w = threadIdx.x >> 6;
    const int lane = threadIdx.x & 63;
    const int col = lane & 15;
    const int quad = lane >> 4;
    const int m0 = mtile * 128 + w * 32;
    const floatx4 fzero = {0.f, 0.f, 0.f, 0.f};
    const float L2E = 1.44269504088896340736f;

    // Q frags (B operand of swapped QK), position-indexed, register-resident
    short8 qf[2][4];
#pragma unroll
    for (int ms = 0; ms < 2; ++ms) {
        const int gq = (m0 >> 4) + ms;
#pragma unroll
        for (int t = 0; t < 4; ++t)
            qf[ms][t] = *(const short8*)&kfrag[((size_t)(b * NGRP + gq) * 4 + t) * 512 + lane * 8];
    }
    // stabilizer of the ACTUAL query at position col of subtile ms
    const int mq = 8 * (col >> 2) + (col & 3);
    float nmreg[2];
    nmreg[0] = -m2[(size_t)b * NN + m0 + mq];
    nmreg[1] = -m2[(size_t)b * NN + m0 + mq + 4];

    floatx4 oacc[2][8];
#pragma unroll
    for (int ms = 0; ms < 2; ++ms)
#pragma unroll
        for (int s8 = 0; s8 < 8; ++s8) oacc[ms][s8] = fzero;

    // 32 x 1KB pieces per chunk (16 K + 16 V); wave w stages 8
    auto stage = [&](int ch, int sel) {
        if (w < 2) {
            const int g16b = split * (KSPLIT >> 4) + ch * 4;
#pragma unroll
            for (int i = 0; i < 8; ++i) {
                int p = w * 8 + i;
                const unsigned short* src =
                    kfrag + ((size_t)(b * NGRP + g16b + (p >> 2)) * 4 + (p & 3)) * 512 + lane * 8;
                gl16(src, &kbuf[sel][p * 512]);
            }
        } else {
            const int g32b = split * (KSPLIT >> 5) + ch * 2;
#pragma unroll
            for (int i = 0; i < 8; ++i) {
                int q = (w - 2) * 8 + i;
                const unsigned short* src =
                    vfrag + ((size_t)(b * NG32 + g32b + (q >> 3)) * 8 + (q & 7)) * 512 + lane * 8;
                gl16(src, &vbuf[sel][q * 512]);
            }
        }
    };

    stage(0, 0);
#pragma unroll 2
    for (int ch = 0; ch < NCHUNK; ++ch) {
        const int sel = ch & 1;
        __syncthreads();                       // drains staging DMA + guards buffer reuse
        if (ch + 1 < NCHUNK) stage(ch + 1, sel ^ 1);
        // ---- S^T = K Q^T over 64 key-positions ----
        floatx4 st[2][4];
#pragma unroll
        for (int ms = 0; ms < 2; ++ms)
#pragma unroll
            for (int u = 0; u < 4; ++u) st[ms][u] = fzero;
#pragma unroll
        for (int t = 0; t < 4; ++t) {
#pragma unroll
            for (int u = 0; u < 4; ++u) {
                short8 kf = *(const short8*)&kbuf[sel][((u * 4 + t) * 64 + lane) * 8];
                st[0][u] = __builtin_amdgcn_mfma_f32_16x16x32_bf16(kf, qf[0][t], st[0][u], 0, 0, 0);
                st[1][u] = __builtin_amdgcn_mfma_f32_16x16x32_bf16(kf, qf[1][t], st[1][u], 0, 0, 0);
            }
        }
        // ---- softmax numerator -> K=32 PV A-frags (registers only) ----
        float ev[2][4][4];
#pragma unroll
        for (int ms = 0; ms < 2; ++ms)
#pragma unroll
            for (int u = 0; u < 4; ++u)
#pragma unroll
                for (int r = 0; r < 4; ++r)
                    ev[ms][u][r] = exp2f(__builtin_fmaf(st[ms][u][r], L2E, nmreg[ms]));
        PK8 af[2][2];
#pragma unroll
        for (int ms = 0; ms < 2; ++ms)
#pragma unroll
            for (int u2 = 0; u2 < 2; ++u2) {
                af[ms][u2].u[0] = pkbf(ev[ms][2 * u2][0], ev[ms][2 * u2][1]);
                af[ms][u2].u[1] = pkbf(ev[ms][2 * u2][2], ev[ms][2 * u2][3]);
                af[ms][u2].u[2] = pkbf(ev[ms][2 * u2 + 1][0], ev[ms][2 * u2 + 1][1]);
                af[ms][u2].u[3] = pkbf(ev[ms][2 * u2 + 1][2], ev[ms][2 * u2 + 1][3]);
            }
        // ---- O += P V (full-rate K=32 MFMAs) ----
#pragma unroll
        for (int u2 = 0; u2 < 2; ++u2) {
#pragma unroll
            for (int s8 = 0; s8 < 8; ++s8) {
                short8 vf = *(const short8*)&vbuf[sel][((u2 * 8 + s8) * 64 + lane) * 8];
                oacc[0][s8] = __builtin_amdgcn_mfma_f32_16x16x32_bf16(af[0][u2].s, vf, oacc[0][s8], 0, 0, 0);
                oacc[1][s8] = __builtin_amdgcn_mfma_f32_16x16x32_bf16(af[1][u2].s, vf, oacc[1][s8], 0, 0, 0);
            }
        }
    }
    // ---- epilogue: position -> actual query remap, bf16 partials ----
    unsigned short* ob = opart + (size_t)(split * BB + b) * NN * CP;
#pragma unroll
    for (int ms = 0; ms < 2; ++ms)
#pragma unroll
        for (int s8 = 0; s8 < 8; ++s8)
#pragma unroll
            for (int r = 0; r < 4; ++r)
                ob[(size_t)(m0 + 8 * quad + 4 * ms + r) * CP + s8 * 16 + col] = f2bf_fast(oacc[ms][s8][r]);
}

// ---------------------------------------------------------------------------
// Linear combine of 4 split partials (L from channel 124) + normalize +
// gamma*E + x; LDS transpose for contiguous [b][c][m] writes.
// ---------------------------------------------------------------------------
__global__ __launch_bounds__(256) void combine_kernel(const unsigned short* __restrict__ opart,
                                                      const float* __restrict__ x,
                                                      const float* __restrict__ gamma,
                                                      float* __restrict__ out) {
    __shared__ float es[32 * 133];
    __shared__ float Lsh[32];
    const int t = threadIdx.x;
    const int b = blockIdx.y;
    const int m0 = blockIdx.x * 32;
    if (t < 32) {
        float L = 0.f;
#pragma unroll
        for (int s = 0; s < NSPLIT; ++s)
            L += bf2f(opart[((size_t)(s * BB + b) * NN + m0 + t) * CP + 124]);
        Lsh[t] = gamma[0] / L;
    }
    const int tc = t & 31, tm = t >> 5;
    float acc[4][4];
#pragma unroll
    for (int i = 0; i < 4; ++i)
#pragma unroll
        for (int j = 0; j < 4; ++j) acc[i][j] = 0.f;
    for (int s = 0; s < NSPLIT; ++s) {
        const unsigned short* obp = opart + ((size_t)(s * BB + b) * NN + m0 + tm * 4) * CP + tc * 4;
#pragma unroll
        for (int i = 0; i < 4; ++i) {
            short4v v = *(const short4v*)(obp + (size_t)i * CP);
            acc[i][0] += bf2f((unsigned short)v[0]);
            acc[i][1] += bf2f((unsigned short)v[1]);
            acc[i][2] += bf2f((unsigned short)v[2]);
            acc[i][3] += bf2f((unsigned short)v[3]);
        }
    }
#pragma unroll
    for (int i = 0; i < 4; ++i)
#pragma unroll
        for (int j = 0; j < 4; ++j) es[(tm * 4 + i) * 133 + tc * 4 + j] = acc[i][j];
    __syncthreads();
    const int wave = t >> 6, lane = t & 63;
    const int half = lane >> 5, lm = lane & 31;
#pragma unroll
    for (int p = 0; p < 16; ++p) {
        int c = p * 8 + wave * 2 + half;
        if (c < CC) {
            size_t base = ((size_t)b * CC + c) * NN + m0 + lm;
            out[base] = es[lm * 133 + c] * Lsh[lm] + x[base];
        }
    }
}

extern "C" void kernel_launch(void* const* d_in, const int* in_sizes, int n_in,
                              void* d_out, int out_size, void* d_ws, size_t ws_size,
                              hipStream_t stream) {
    const float* x = (const float*)d_in[0];
    const float* Wb = (const float*)d_in[1];
    const float* gamma = (const float*)d_in[2];
    float* out = (float*)d_out;

    const size_t kfrag_b = (size_t)BB * NGRP * 4 * 64 * 8 * sizeof(unsigned short);   // 4 MB
    const size_t vfrag_b = (size_t)BB * NG32 * 8 * 64 * 8 * sizeof(unsigned short);   // 4 MB
    const size_t m2_b = (size_t)BB * NN * sizeof(float);                               // 64 KB
    const size_t opart_b = (size_t)NSPLIT * BB * NN * CP * sizeof(unsigned short);     // 16 MB
    const size_t wbt_b = (size_t)CC * CP * sizeof(unsigned short);                     // 32 KB
    if (ws_size < kfrag_b + vfrag_b + m2_b + opart_b + wbt_b) return;

    char* w = (char*)d_ws;
    unsigned short* kfrag = (unsigned short*)w;
    unsigned short* vfrag = (unsigned short*)(w + kfrag_b);
    float* m2 = (float*)(w + kfrag_b + vfrag_b);
    unsigned short* opart = (unsigned short*)(w + kfrag_b + vfrag_b + m2_b);
    unsigned short* wbt = (unsigned short*)(w + kfrag_b + vfrag_b + m2_b + opart_b);

    wtrans_kernel<<<dim3(4), 256, 0, stream>>>(Wb, wbt);
    bf_proj_kernel<<<dim3(NN / 32, BB), 256, 0, stream>>>(x, wbt, kfrag, vfrag, m2);
    attn_kernel<<<dim3(512), 256, 0, stream>>>(kfrag, vfrag, m2, opart);
    combine_kernel<<<dim3(NN / 32, BB), 256, 0, stream>>>(opart, x, gamma, out);
}